// Round 2
// baseline (199.144 us; speedup 1.0000x reference)
//
#include <hip/hip_runtime.h>

// QNN closed form: q_b = prod_{i<8} cos(pi/2 + 2*x_bi) = prod_{i<8} sin(2*x_bi)
// (8 negative signs cancel). out[b,0] = s*q, out[b,1] = -s*q.
//
// Coalescing scheme: chunk index i covers float4 #i of x (two chunks per row).
// A thread loads the float4, forms a 4-factor partial product, exchanges with
// its partner lane (lane^1) via __shfl_xor to get the full 8-factor product,
// and writes out[i] (= out[row=i>>1][col=i&1]). Loads are 16B/lane contiguous,
// stores 4B/lane contiguous — both perfectly coalesced, no LDS needed.
//
// Grid-stride with a 2048-block cap (Guideline 11): 524,288 threads, 16 chunks
// each — amortizes index/bounds overhead, keeps pairing intact because the
// stride is even (lanes 2j/2j+1 always hold chunks 2i/2i+1 of the same row).
//
// NOTE (round-1 lesson): in_sizes[] is in ELEMENTS, not bytes. in_sizes[0] =
// B*8 floats; /4 gives the float4-chunk count (= B*2 = out element count).

__global__ __launch_bounds__(256) void qnn_kernel(const float4* __restrict__ x4,
                                                  const float* __restrict__ scale_p,
                                                  float* __restrict__ out,
                                                  int n4) {
    const int stride = gridDim.x * blockDim.x;   // multiple of 2 by construction
    const float s = scale_p[0];                  // uniform -> scalar load

    for (int i = blockIdx.x * blockDim.x + threadIdx.x; i < n4; i += stride) {
        float4 v = x4[i];
        // __sinf: v_mul (1/2pi) + v_sin_f32. |2x| <~ 12 rad for N(0,1) -> accurate.
        float p = __sinf(2.0f * v.x) * __sinf(2.0f * v.y) *
                  __sinf(2.0f * v.z) * __sinf(2.0f * v.w);

        float q = p * __shfl_xor(p, 1, 64);      // full 8-factor row product

        out[i] = (i & 1) ? (-s * q) : (s * q);
    }
}

extern "C" void kernel_launch(void* const* d_in, const int* in_sizes, int n_in,
                              void* d_out, int out_size, void* d_ws, size_t ws_size,
                              hipStream_t stream) {
    const float4* x4    = (const float4*)d_in[0];   // [B,8] fp32 viewed as [B*2] float4
    const float*  scale = (const float*)d_in[2];    // scalar (d_in[1] = weights, unused)
    float*        out   = (float*)d_out;            // [B,2] fp32 flat = B*2 floats

    int n4 = in_sizes[0] / 4;                       // in_sizes is ELEMENT count: B*8/4 = B*2 chunks
    int block = 256;
    int grid = (n4 + block - 1) / block;
    if (grid > 2048) grid = 2048;                   // Guideline 11: cap + grid-stride
    qnn_kernel<<<grid, block, 0, stream>>>(x4, scale, out, n4);
}

// Round 3
// 197.210 us; speedup vs baseline: 1.0098x; 1.0098x over previous
//
#include <hip/hip_runtime.h>

// QNN closed form: q_b = prod_{i<8} cos(pi/2 + 2*x_bi) = prod_{i<8} sin(2*x_bi)
// (8 negative signs cancel). out[b,0] = s*q, out[b,1] = -s*q.
//
// Row-per-thread scheme (round 2): thread r loads the full row b=r as two
// adjacent float4s (32 B/lane; the wave's two load instructions jointly cover
// a dense 2 KiB segment — the second load L1-hits the lines the first
// fetched), computes the 8-factor sin product, and stores BOTH outputs as one
// float2 {s*q, -s*q} (8 B/lane, 512 B/wave contiguous). vs the prior
// chunk+shfl scheme this removes the cross-lane shuffle, the parity select,
// and halves the number of store instructions — the kernel is issue-bound,
// not HBM-bound (x fits the 256 MiB L3 across replays), so instructions per
// byte is the lever.
//
// NOTE: in_sizes[] is in ELEMENTS, not bytes. in_sizes[0] = B*8 floats.

__global__ __launch_bounds__(256) void qnn_kernel(const float4* __restrict__ x4,
                                                  const float* __restrict__ scale_p,
                                                  float2* __restrict__ out2,
                                                  int nrows) {
    int r = blockIdx.x * blockDim.x + threadIdx.x;
    if (r >= nrows) return;

    float4 a = x4[2 * r];
    float4 b = x4[2 * r + 1];

    // __sinf: v_mul (1/2pi) + v_sin_f32. |2x| <~ 12 rad for N(0,1) -> accurate.
    float p = __sinf(2.0f * a.x) * __sinf(2.0f * a.y) *
              __sinf(2.0f * a.z) * __sinf(2.0f * a.w);
    float q = __sinf(2.0f * b.x) * __sinf(2.0f * b.y) *
              __sinf(2.0f * b.z) * __sinf(2.0f * b.w) * p;

    float s = scale_p[0];
    out2[r] = make_float2(s * q, -s * q);
}

extern "C" void kernel_launch(void* const* d_in, const int* in_sizes, int n_in,
                              void* d_out, int out_size, void* d_ws, size_t ws_size,
                              hipStream_t stream) {
    const float4* x4    = (const float4*)d_in[0];   // [B,8] fp32 viewed as [B*2] float4
    const float*  scale = (const float*)d_in[2];    // scalar (d_in[1] = weights, unused)
    float2*       out2  = (float2*)d_out;           // [B,2] fp32 = B float2

    int nrows = in_sizes[0] / 8;                    // element count: B*8 floats -> B rows
    int block = 256;
    int grid = (nrows + block - 1) / block;         // B = 4,194,304 -> 16,384 blocks, no tail
    qnn_kernel<<<grid, block, 0, stream>>>(x4, scale, out2, nrows);
}